// Round 2
// baseline (77.314 us; speedup 1.0000x reference)
//
#include <hip/hip_runtime.h>
#include <hip/hip_cooperative_groups.h>

namespace cg = cooperative_groups;

// mi = BETA * sum_d Var_d(y),  y: [1024, 256] fp32.
// (mean_i mean_j (y_jd - y_id)^2 = 2*Var_d; the /2 in the reference cancels.)
//
// Single cooperative kernel: phase 1 per-block column partial sums -> ws,
// grid.sync(), phase 2 (block 0) folds partials into the scalar.

#define N_ROWS 1024
#define D 256
#define NBLK 32
#define ROWS_PER_BLK (N_ROWS / NBLK)   // 32
#define BETA 0.001f

__global__ void club_fused(const float* __restrict__ y, float* __restrict__ ws,
                           float* __restrict__ out) {
    const int d = threadIdx.x;                 // 0..255 (dim)
    const int b = blockIdx.x;                  // 0..31

    // Phase 1: rows [b*32, b*32+32). Each row pass: 256 threads read one
    // contiguous 1 KB row -> fully coalesced.
    const float* p = y + (size_t)b * ROWS_PER_BLK * D + d;
    float s = 0.f, s2 = 0.f;
#pragma unroll
    for (int r = 0; r < ROWS_PER_BLK; ++r) {
        float v = p[r * D];
        s  += v;
        s2 += v * v;
    }
    ws[b * (2 * D) + d]     = s;
    ws[b * (2 * D) + D + d] = s2;

    __threadfence();          // device-scope visibility of ws across XCDs
    cg::this_grid().sync();

    // Phase 2: block 0 only.
    if (b == 0) {
        float ts = 0.f, ts2 = 0.f;
#pragma unroll 8
        for (int g = 0; g < NBLK; ++g) {
            ts  += ws[g * (2 * D) + d];
            ts2 += ws[g * (2 * D) + D + d];
        }
        const float invN = 1.0f / (float)N_ROWS;
        float mu = ts * invN;
        float v  = ts2 * invN - mu * mu;       // per-dim variance

        // wave(64) shuffle reduction, then 4 waves via LDS
#pragma unroll
        for (int off = 32; off > 0; off >>= 1)
            v += __shfl_down(v, off, 64);

        __shared__ float lds[4];
        const int wave = threadIdx.x >> 6;
        const int lane = threadIdx.x & 63;
        if (lane == 0) lds[wave] = v;
        __syncthreads();
        if (threadIdx.x == 0)
            out[0] = (lds[0] + lds[1] + lds[2] + lds[3]) * BETA;
    }
}

extern "C" void kernel_launch(void* const* d_in, const int* in_sizes, int n_in,
                              void* d_out, int out_size, void* d_ws, size_t ws_size,
                              hipStream_t stream) {
    const float* y  = (const float*)d_in[0];
    float* ws       = (float*)d_ws;            // uses NBLK*2*D*4 = 64 KB
    float* out      = (float*)d_out;

    void* args[] = { (void*)&y, (void*)&ws, (void*)&out };
    hipLaunchCooperativeKernel((void*)club_fused, dim3(NBLK), dim3(D),
                               args, 0, stream);
}

// Round 3
// 57.573 us; speedup vs baseline: 1.3429x; 1.3429x over previous
//
#include <hip/hip_runtime.h>

// mi = BETA * sum_d Var_d(y),  y: [1024, 256] fp32.
// (mean_i mean_j (y_jd - y_id)^2 = 2*Var_d; the /2 in the reference cancels.)
//
// Single plain kernel, last-block-done: each block writes column partial
// sums to ws, takes an atomic ticket; the last block folds partials and
// writes the scalar. Works under 0xAA-poisoned ws: ticket base is either
// 0 (zeroed) or 0xAAAAAAAA (poisoned), both detected.

#define N_ROWS 1024
#define D 256
#define NBLK 32
#define ROWS_PER_BLK (N_ROWS / NBLK)   // 32
#define BETA 0.001f
#define POISON 0xAAAAAAAAu

__global__ void club_onepass(const float* __restrict__ y, float* __restrict__ ws,
                             unsigned* __restrict__ counter, float* __restrict__ out) {
    const int d = threadIdx.x;                 // 0..255 (dim)
    const int b = blockIdx.x;                  // 0..31

    // Phase 1: rows [b*32, b*32+32). Each row pass: 256 threads read one
    // contiguous 1 KB row -> fully coalesced.
    const float* p = y + (size_t)b * ROWS_PER_BLK * D + d;
    float s = 0.f, s2 = 0.f;
#pragma unroll
    for (int r = 0; r < ROWS_PER_BLK; ++r) {
        float v = p[r * D];
        s  += v;
        s2 += v * v;
    }
    ws[b * (2 * D) + d]     = s;
    ws[b * (2 * D) + D + d] = s2;

    __threadfence();                           // release partials (device scope)

    // Ticket: last block to arrive does the final fold.
    __shared__ int is_last;
    if (threadIdx.x == 0) {
        unsigned old = atomicAdd(counter, 1u); // device-scope by default
        is_last = (old == NBLK - 1u) || (old == POISON + NBLK - 1u);
    }
    __syncthreads();

    if (is_last) {
        __threadfence();                       // acquire partials
        float ts = 0.f, ts2 = 0.f;
#pragma unroll 8
        for (int g = 0; g < NBLK; ++g) {
            ts  += ws[g * (2 * D) + d];
            ts2 += ws[g * (2 * D) + D + d];
        }
        const float invN = 1.0f / (float)N_ROWS;
        float mu = ts * invN;
        float v  = ts2 * invN - mu * mu;       // per-dim variance

#pragma unroll
        for (int off = 32; off > 0; off >>= 1)
            v += __shfl_down(v, off, 64);

        __shared__ float lds[4];
        const int wave = threadIdx.x >> 6;
        const int lane = threadIdx.x & 63;
        if (lane == 0) lds[wave] = v;
        __syncthreads();
        if (threadIdx.x == 0)
            out[0] = (lds[0] + lds[1] + lds[2] + lds[3]) * BETA;
    }
}

extern "C" void kernel_launch(void* const* d_in, const int* in_sizes, int n_in,
                              void* d_out, int out_size, void* d_ws, size_t ws_size,
                              hipStream_t stream) {
    const float* y  = (const float*)d_in[0];
    float* ws       = (float*)d_ws;                          // partials: 64 KB
    unsigned* ctr   = (unsigned*)((char*)d_ws + NBLK * 2 * D * sizeof(float));
    float* out      = (float*)d_out;

    club_onepass<<<NBLK, D, 0, stream>>>(y, ws, ctr, out);
}

// Round 4
// 56.879 us; speedup vs baseline: 1.3593x; 1.0122x over previous
//
#include <hip/hip_runtime.h>

// mi = BETA * sum_d Var_d(y),  y: [1024, 256] fp32.
// Derivation: mean_i mean_j (y_jd - y_id)^2 = 2*Var_d; the /2 cancels.
//
// Best-measured variant (R1, 56.3 us): two plain graph dispatches.
// dur_us is dominated by the harness's 256 MiB d_ws re-poison
// (~40 us fillBufferAligned @ 83% HBM peak) + reset machinery; our two
// kernels are ~2-4 us total. Cooperative launch (R2) cost +20 us;
// last-block-done (R3) was neutral-to-slightly-worse vs this.

#define N_ROWS 1024
#define D 256
#define NBLK 64
#define ROWS_PER_BLK (N_ROWS / NBLK)   // 16
#define BETA 0.001f

// Kernel 1: block b handles rows [b*16, b*16+16); thread d = dim d.
// Each row pass: 256 threads read one contiguous 1 KB row (coalesced).
__global__ void club_partial(const float* __restrict__ y, float* __restrict__ ws) {
    const int d = threadIdx.x;                 // 0..255
    const int b = blockIdx.x;                  // 0..63
    const float* p = y + (size_t)b * ROWS_PER_BLK * D + d;
    float s = 0.f, s2 = 0.f;
#pragma unroll
    for (int r = 0; r < ROWS_PER_BLK; ++r) {
        float v = p[r * D];
        s  += v;
        s2 += v * v;
    }
    ws[b * (2 * D) + d]     = s;
    ws[b * (2 * D) + D + d] = s2;
}

// Kernel 2: one block, 256 threads. Thread d folds the 64 block-partials,
// forms the per-dim variance, then block-reduces to the scalar.
__global__ void club_final(const float* __restrict__ ws, float* __restrict__ out) {
    const int d = threadIdx.x;
    float s = 0.f, s2 = 0.f;
#pragma unroll 8
    for (int g = 0; g < NBLK; ++g) {
        s  += ws[g * (2 * D) + d];
        s2 += ws[g * (2 * D) + D + d];
    }
    const float invN = 1.0f / (float)N_ROWS;
    float mu = s * invN;
    float v  = s2 * invN - mu * mu;   // per-dim variance contribution

    // wave(64)-level shuffle reduction
#pragma unroll
    for (int off = 32; off > 0; off >>= 1)
        v += __shfl_down(v, off, 64);

    __shared__ float lds[4];
    const int wave = threadIdx.x >> 6;
    const int lane = threadIdx.x & 63;
    if (lane == 0) lds[wave] = v;
    __syncthreads();
    if (threadIdx.x == 0) {
        float t = lds[0] + lds[1] + lds[2] + lds[3];
        out[0] = t * BETA;
    }
}

extern "C" void kernel_launch(void* const* d_in, const int* in_sizes, int n_in,
                              void* d_out, int out_size, void* d_ws, size_t ws_size,
                              hipStream_t stream) {
    const float* y = (const float*)d_in[0];
    float* ws = (float*)d_ws;          // uses NBLK*2*D*4 = 128 KB
    float* out = (float*)d_out;

    club_partial<<<NBLK, D, 0, stream>>>(y, ws);
    club_final<<<1, D, 0, stream>>>(ws, out);
}